// Round 7
// baseline (530.547 us; speedup 1.0000x reference)
//
#include <hip/hip_runtime.h>
#include <hip/hip_bf16.h>

typedef __bf16 bf16x8  __attribute__((ext_vector_type(8)));
typedef __bf16 bf16x16 __attribute__((ext_vector_type(16)));
typedef float  f32x4   __attribute__((ext_vector_type(4)));

#define N_IN   4096
#define N_OUT  1024
#define BATCH  16
#define ROWS   16

// LDS strides in __bf16 elements
#define H1_STR   72     // 64 + 8
#define H2_STR   72
#define FT_JSTR  40     // 32 + 8  (filtT j-stride)
#define FT_NSTR  1280   // 32*40   (filtT n-stride)
#define G_STR    520    // 512 + 8
#define V_STR    520

// ws layout:
//   [0,131072)       w3t  bf16 (1024x64)       w3t[col*64+k]
//   [131072,139264)  w2t  bf16 (64x64)         w2t[col*64+k]
//   [139264,4333568) featT bf16 (32*4096*16)   featT[((c*4096+src)*16)+b]
#define WS_W3T_OFF    0
#define WS_W2T_OFF    131072
#define WS_FEATT_OFF  139264
#define WS_NEED       4333568

__global__ void qc_zero_kernel(float* __restrict__ out, int n4) {
    int i = blockIdx.x * blockDim.x + threadIdx.x;
    if (i < n4) ((float4*)out)[i] = make_float4(0.f, 0.f, 0.f, 0.f);
}

// Fallback prep: w3t/w2t only
__global__ void qc_prep_kernel(const float* __restrict__ w3, const float* __restrict__ w2,
                               __bf16* __restrict__ w3t, __bf16* __restrict__ w2t) {
    int gid = blockIdx.x * blockDim.x + threadIdx.x;
    if (gid < 65536) {
        int k = gid & 63, col = gid >> 6;
        w3t[gid] = (__bf16)w3[k * 1024 + col];
    } else {
        int j = gid - 65536;
        int k = j & 63, col = j >> 6;
        w2t[j] = (__bf16)w2[k * 64 + col];
    }
}

// Fused prep: zero out (512 blks) + w3t (256) + w2t (16) + featT transpose (512)
__global__ void qc_prep2_kernel(const float* __restrict__ w3, const float* __restrict__ w2,
                                const float* __restrict__ feat,
                                float* __restrict__ out,
                                __bf16* __restrict__ w3t, __bf16* __restrict__ w2t,
                                __bf16* __restrict__ featT) {
    int bid = blockIdx.x, tid = threadIdx.x;
    if (bid < 512) {
        int i = bid * 256 + tid;                     // 131072 float4s
        ((float4*)out)[i] = make_float4(0.f, 0.f, 0.f, 0.f);
    } else if (bid < 768) {
        int gid = (bid - 512) * 256 + tid;           // 65536
        int k = gid & 63, col = gid >> 6;
        w3t[gid] = (__bf16)w3[k * 1024 + col];
    } else if (bid < 784) {
        int j = (bid - 768) * 256 + tid;             // 4096
        int k = j & 63, col = j >> 6;
        w2t[j] = (__bf16)w2[k * 64 + col];
    } else {
        // featT[c][src][b] = feat[b][c][src]; 512 blocks cover 32 c x 16 chunks
        int bid2 = bid - 784;                        // 0..511
        int c    = bid2 >> 4;                        // 0..31
        int src  = (bid2 & 15) * 256 + tid;          // 0..4095
        bf16x16 v;
        #pragma unroll
        for (int b = 0; b < 16; ++b)                 // coalesced dword loads per b
            v[b] = (__bf16)feat[(b * 32 + c) * N_IN + src];
        __bf16* p = &featT[((size_t)c * N_IN + src) * 16];   // 32B/thread, coalesced
        *(bf16x8*)p       = *(bf16x8*)&v;
        *(bf16x8*)(p + 8) = *((bf16x8*)&v + 1);
    }
}

// ---------------------------------------------------------------------------
// Fused kernel: 512 threads per 16-row tile.
//   [1x32B featT gather/thread] + idx/h1 -> S1 -> h2 (MFMA) -> S2 ->
//   filt (MFMA -> LDS) + key build -> park gather -> S3 ->
//   einsum (MFMA) -> vals -> S4 -> segmented-run reduction:
//   interior runs = plain store, block-edge runs = atomicAdd.
// ---------------------------------------------------------------------------
__global__ __launch_bounds__(512, 4)
void qc_fused_kernel(const __bf16* __restrict__ featT,
                     const float* __restrict__ w1,
                     const float* __restrict__ locs,
                     const int*   __restrict__ eidx,
                     const __bf16* __restrict__ w2t,
                     const __bf16* __restrict__ w3t,
                     float* __restrict__ out,
                     int E)
{
    __shared__ __align__(16) __bf16 h1b[ROWS * H1_STR];   // 2304 B (later: kbuf)
    __shared__ __align__(16) __bf16 h2b[ROWS * H2_STR];   // 2304 B
    __shared__ __align__(16) __bf16 ftv[ROWS * FT_NSTR];  // 40960 B
    __shared__ __align__(16) __bf16 gb [BATCH * G_STR];   // 16640 B (later: vals)
    __shared__ unsigned short seg_s[512];                 // 1024 B
    // total 63232 B -> 2 blocks/CU

    const int tid = threadIdx.x;
    const int n0  = blockIdx.x * ROWS;
    const int t0  = n0 * 32;
    const int ch0 = t0 / E;
    const int m0  = t0 - ch0 * E;          // block spans <512 t's -> at most one wrap

    // ---- Gather: ONE 32B load per thread (all 16 batches), issued first ----
    int mm = m0 + tid;
    const int cc = ch0 + (mm >= E);
    if (mm >= E) mm -= E;
    int2 p = ((const int2*)eidx)[mm];      // .x = seg, .y = src
    bf16x16 gv = {};
    if (cc < 32)
        gv = *(const bf16x16*)&featT[((size_t)cc * N_IN + p.y) * 16];
    seg_s[tid] = (unsigned short)p.x;

    // ---- Phase A: h1 = sin(loc @ W1) ----
    {
        const int r  = tid >> 5;
        const int j0 = (tid & 31) * 2;
        float lx = 0.f, ly = 0.f;
        int n = n0 + r;
        if (n < E) { lx = locs[n * 2]; ly = locs[n * 2 + 1]; }
        float2 wa = *(const float2*)&w1[j0];
        float2 wb = *(const float2*)&w1[64 + j0];
        __bf16* h = &h1b[r * H1_STR + j0];
        h[0] = (__bf16)__sinf(lx * wa.x + ly * wb.x);
        h[1] = (__bf16)__sinf(lx * wa.y + ly * wb.y);
    }
    __syncthreads();   // S1

    const int lane = tid & 63;
    const int wv   = tid >> 6;      // 0..7
    const int ml   = lane & 15;
    const int q    = lane >> 4;

    // ---- Phase B: h2 = sin(h1 @ W2) via MFMA (waves 0..3, 16 cols each) ----
    if (wv < 4) {
        bf16x8 a0 = *(const bf16x8*)&h1b[ml * H1_STR + q * 8];
        bf16x8 a1 = *(const bf16x8*)&h1b[ml * H1_STR + 32 + q * 8];
        const __bf16* wp = &w2t[(wv * 16 + ml) * 64 + q * 8];
        bf16x8 b0 = *(const bf16x8*)wp;
        bf16x8 b1 = *(const bf16x8*)(wp + 32);
        f32x4 c = {0.f, 0.f, 0.f, 0.f};
        c = __builtin_amdgcn_mfma_f32_16x16x32_bf16(a0, b0, c, 0, 0, 0);
        c = __builtin_amdgcn_mfma_f32_16x16x32_bf16(a1, b1, c, 0, 0, 0);
        #pragma unroll
        for (int g_ = 0; g_ < 4; ++g_)
            h2b[(q * 4 + g_) * H2_STR + wv * 16 + ml] = (__bf16)__sinf(c[g_]);
    }
    __syncthreads();   // S2  (h1b dead after this -> reused as kbuf)

    int* kbuf = (int*)h1b;   // 512 ints = 2048 B <= 2304 B

    // ---- Phase C: filt = h2 @ W3 via MFMA; filtT[n][j][i] into LDS ----
    {
        bf16x8 a0 = *(const bf16x8*)&h2b[ml * H2_STR + q * 8];
        bf16x8 a1 = *(const bf16x8*)&h2b[ml * H2_STR + 32 + q * 8];
        #pragma unroll
        for (int t = 0; t < 8; ++t) {
            int col = wv * 128 + t * 16 + ml;          // = i*32 + j
            const __bf16* wp = &w3t[col * 64 + q * 8];
            bf16x8 b0 = *(const bf16x8*)wp;
            bf16x8 b1 = *(const bf16x8*)(wp + 32);
            f32x4 c = {0.f, 0.f, 0.f, 0.f};
            c = __builtin_amdgcn_mfma_f32_16x16x32_bf16(a0, b0, c, 0, 0, 0);
            c = __builtin_amdgcn_mfma_f32_16x16x32_bf16(a1, b1, c, 0, 0, 0);
            int i_ = col >> 5, j_ = col & 31;
            __bf16* fp = &ftv[j_ * FT_JSTR + i_];
            fp[(q * 4 + 0) * FT_NSTR] = (__bf16)c[0];
            fp[(q * 4 + 1) * FT_NSTR] = (__bf16)c[1];
            fp[(q * 4 + 2) * FT_NSTR] = (__bf16)c[2];
            fp[(q * 4 + 3) * FT_NSTR] = (__bf16)c[3];
        }
    }
    // ---- Build scatter keys (one per tl); invalid -> unique negative ----
    {
        int mm2 = m0 + tid;
        int cc2 = ch0 + (mm2 >= E);
        kbuf[tid] = (cc2 < 32) ? ((cc2 << 10) | (int)seg_s[tid]) : -(tid + 1);
    }
    // ---- Park gathered batches into gb (stride-1 writes) ----
    #pragma unroll
    for (int b = 0; b < 16; ++b)
        gb[b * G_STR + tid] = gv[b];
    __syncthreads();   // S3

    // ---- Phase D: vals[b][j] = g[b][:] @ filt[r]; 8 waves x 2 rows ----
    {
        bf16x8 ag[2], f0[2], f1[2];
        #pragma unroll
        for (int rr = 0; rr < 2; ++rr) {
            int r = wv * 2 + rr;
            f0[rr] = *(const bf16x8*)&ftv[r * FT_NSTR + ml        * FT_JSTR + q * 8];
            f1[rr] = *(const bf16x8*)&ftv[r * FT_NSTR + (16 + ml) * FT_JSTR + q * 8];
            ag[rr] = *(const bf16x8*)&gb[ml * G_STR + r * 32 + q * 8];
        }
        f32x4 c0[2], c1[2];
        #pragma unroll
        for (int rr = 0; rr < 2; ++rr) {
            f32x4 z = {0.f, 0.f, 0.f, 0.f};
            c0[rr] = __builtin_amdgcn_mfma_f32_16x16x32_bf16(ag[rr], f0[rr], z, 0, 0, 0);
            c1[rr] = __builtin_amdgcn_mfma_f32_16x16x32_bf16(ag[rr], f1[rr], z, 0, 0, 0);
        }
        __syncthreads();   // S4a: gb reads done; overlay vals onto gb
        __bf16* valsb = gb;
        #pragma unroll
        for (int rr = 0; rr < 2; ++rr) {
            int r = wv * 2 + rr;
            __bf16* vp = &valsb[r * 32];
            #pragma unroll
            for (int g_ = 0; g_ < 4; ++g_) {
                int b = q * 4 + g_;
                vp[b * V_STR + ml]      = (__bf16)c0[rr][g_];
                vp[b * V_STR + 16 + ml] = (__bf16)c1[rr][g_];
            }
        }
    }
    __syncthreads();   // S4b

    // ---- Phase E: segmented-run reduction + store/atomic ----
    // 16 b x 32 windows of 16 tl. Run = maximal key-equal span. A thread
    // owning a run START scans to its end, sums vals[b][s..e), then:
    //   interior run (s>0 && e<512)  -> plain store (sole writer)
    //   edge run                     -> atomicAdd (other block may add too)
    {
        const __bf16* valsb = gb;
        const int b   = tid >> 5;             // 0..15
        const int w16 = (tid & 31) * 16;      // window start
        int kprev = (w16 == 0) ? 0x7fffffff : kbuf[w16 - 1];
        for (int s = w16; s < w16 + 16; ++s) {
            int k = kbuf[s];
            bool isStart = (k != kprev);
            kprev = k;
            if (!isStart) continue;
            int e = s + 1;
            while (e < 512 && kbuf[e] == k) ++e;
            float acc = 0.f;
            for (int t = s; t < e; ++t)
                acc += (float)valsb[b * V_STR + t];
            if (k >= 0) {
                float* dst = &out[(b << 15) + k];
                if (s > 0 && e < 512) *dst = acc;
                else atomicAdd(dst, acc);
            }
        }
    }
}

// ---------------------------------------------------------------------------
// Fallback: round-1 fused kernel (used only if ws too small)
// ---------------------------------------------------------------------------
#define FB_FT_NSTR 1288
__global__ __launch_bounds__(256, 2)
void qc_main_kernel(const float* __restrict__ feat,
                    const float* __restrict__ w1,
                    const float* __restrict__ w2,
                    const float* __restrict__ locs,
                    const int*   __restrict__ eidx,
                    const __bf16* __restrict__ w3t,
                    float* __restrict__ out,
                    int E)
{
    __shared__ __align__(16) __bf16 h1b[ROWS * H1_STR];
    __shared__ __align__(16) __bf16 h2b[ROWS * H2_STR];
    __shared__ __align__(16) __bf16 ftv[ROWS * FB_FT_NSTR];
    __shared__ __align__(16) __bf16 gb [BATCH * G_STR];
    __shared__ unsigned short seg_s[512];
    __shared__ unsigned short src_s[512];

    const int tid = threadIdx.x;
    const int n0  = blockIdx.x * ROWS;
    const int t0  = n0 * 32;
    const int ch0 = t0 / E;
    const int m0  = t0 - ch0 * E;

    {
        const int r  = tid >> 4;
        const int j0 = (tid & 15) * 4;
        float lx = 0.f, ly = 0.f;
        int n = n0 + r;
        if (n < E) { lx = locs[n * 2]; ly = locs[n * 2 + 1]; }
        float4 wa = *(const float4*)&w1[j0];
        float4 wb = *(const float4*)&w1[64 + j0];
        __bf16* h = &h1b[r * H1_STR + j0];
        h[0] = (__bf16)__sinf(lx * wa.x + ly * wb.x);
        h[1] = (__bf16)__sinf(lx * wa.y + ly * wb.y);
        h[2] = (__bf16)__sinf(lx * wa.z + ly * wb.z);
        h[3] = (__bf16)__sinf(lx * wa.w + ly * wb.w);
    }
    for (int tl = tid; tl < 512; tl += 256) {
        int mm = m0 + tl; if (mm >= E) mm -= E;
        seg_s[tl] = (unsigned short)eidx[mm * 2];
        src_s[tl] = (unsigned short)eidx[mm * 2 + 1];
    }
    __syncthreads();

    {
        const int r  = tid >> 4;
        const int j0 = (tid & 15) * 4;
        float a0 = 0.f, a1 = 0.f, a2 = 0.f, a3 = 0.f;
        const __bf16* h1r = &h1b[r * H1_STR];
        #pragma unroll 8
        for (int k = 0; k < 64; ++k) {
            float h = (float)h1r[k];
            float4 w = *(const float4*)&w2[k * 64 + j0];
            a0 += h * w.x; a1 += h * w.y; a2 += h * w.z; a3 += h * w.w;
        }
        __bf16* h = &h2b[r * H2_STR + j0];
        h[0] = (__bf16)__sinf(a0);
        h[1] = (__bf16)__sinf(a1);
        h[2] = (__bf16)__sinf(a2);
        h[3] = (__bf16)__sinf(a3);
    }
    #pragma unroll 4
    for (int it = 0; it < 32; ++it) {
        int idx = it * 256 + tid;
        int b   = idx >> 9;
        int tl  = idx & 511;
        int mm  = m0 + tl;
        int cc  = ch0 + (mm >= E);
        if (mm >= E) mm -= E;
        float v = 0.f;
        if (cc < 32) v = feat[(b * 32 + cc) * N_IN + (int)src_s[tl]];
        gb[b * G_STR + tl] = (__bf16)v;
    }
    __syncthreads();

    const int lane = tid & 63;
    const int wv   = tid >> 6;
    const int ml   = lane & 15;
    const int q    = lane >> 4;

    {
        bf16x8 a0 = *(const bf16x8*)&h2b[ml * H2_STR + q * 8];
        bf16x8 a1 = *(const bf16x8*)&h2b[ml * H2_STR + 32 + q * 8];
        #pragma unroll
        for (int t = 0; t < 16; ++t) {
            int col = wv * 256 + t * 16 + ml;
            const __bf16* wp = &w3t[col * 64 + q * 8];
            bf16x8 b0 = *(const bf16x8*)wp;
            bf16x8 b1 = *(const bf16x8*)(wp + 32);
            f32x4 c = {0.f, 0.f, 0.f, 0.f};
            c = __builtin_amdgcn_mfma_f32_16x16x32_bf16(a0, b0, c, 0, 0, 0);
            c = __builtin_amdgcn_mfma_f32_16x16x32_bf16(a1, b1, c, 0, 0, 0);
            int i_ = col >> 5, j_ = col & 31;
            __bf16* fp = &ftv[j_ * FT_JSTR + i_];
            fp[(q * 4 + 0) * FB_FT_NSTR] = (__bf16)c[0];
            fp[(q * 4 + 1) * FB_FT_NSTR] = (__bf16)c[1];
            fp[(q * 4 + 2) * FB_FT_NSTR] = (__bf16)c[2];
            fp[(q * 4 + 3) * FB_FT_NSTR] = (__bf16)c[3];
        }
    }
    __syncthreads();

    {
        bf16x8 ag[4], f0[4], f1[4];
        #pragma unroll
        for (int rr = 0; rr < 4; ++rr) {
            int r = wv * 4 + rr;
            ag[rr] = *(const bf16x8*)&gb[ml * G_STR + r * 32 + q * 8];
            f0[rr] = *(const bf16x8*)&ftv[r * FB_FT_NSTR + ml        * FT_JSTR + q * 8];
            f1[rr] = *(const bf16x8*)&ftv[r * FB_FT_NSTR + (16 + ml) * FT_JSTR + q * 8];
        }
        __syncthreads();
        __bf16* valsb = ftv;
        #pragma unroll
        for (int rr = 0; rr < 4; ++rr) {
            int r = wv * 4 + rr;
            f32x4 c0 = {0.f, 0.f, 0.f, 0.f};
            f32x4 c1 = {0.f, 0.f, 0.f, 0.f};
            c0 = __builtin_amdgcn_mfma_f32_16x16x32_bf16(ag[rr], f0[rr], c0, 0, 0, 0);
            c1 = __builtin_amdgcn_mfma_f32_16x16x32_bf16(ag[rr], f1[rr], c1, 0, 0, 0);
            __bf16* vp = &valsb[r * 32];
            #pragma unroll
            for (int g_ = 0; g_ < 4; ++g_) {
                int b = q * 4 + g_;
                vp[b * V_STR + ml]      = (__bf16)c0[g_];
                vp[b * V_STR + 16 + ml] = (__bf16)c1[g_];
            }
        }
    }
    __syncthreads();

    {
        const __bf16* valsb = ftv;
        const int b = tid >> 4;
        const int r = tid & 15;
        const __bf16* vp = &valsb[b * V_STR + r * 32];
        bf16x8 v0 = *(const bf16x8*)(vp);
        bf16x8 v1 = *(const bf16x8*)(vp + 8);
        bf16x8 v2 = *(const bf16x8*)(vp + 16);
        bf16x8 v3 = *(const bf16x8*)(vp + 24);
        float vv[32];
        #pragma unroll
        for (int j = 0; j < 8; ++j) {
            vv[j]      = (float)v0[j];
            vv[8 + j]  = (float)v1[j];
            vv[16 + j] = (float)v2[j];
            vv[24 + j] = (float)v3[j];
        }
        const int tl0 = r * 32;
        int key_prev = -1;
        float acc = 0.f;
        #pragma unroll
        for (int j = 0; j < 32; ++j) {
            int mm = m0 + tl0 + j;
            int cc = ch0 + (mm >= E);
            if (mm >= E) mm -= E;
            if (cc < 32) {
                int o   = (int)seg_s[tl0 + j];
                int key = ((b * 32 + cc) << 10) | o;
                if (key != key_prev) {
                    if (key_prev >= 0) atomicAdd(&out[key_prev], acc);
                    key_prev = key;
                    acc = vv[j];
                } else {
                    acc += vv[j];
                }
            }
        }
        if (key_prev >= 0) atomicAdd(&out[key_prev], acc);
    }
}

extern "C" void kernel_launch(void* const* d_in, const int* in_sizes, int n_in,
                              void* d_out, int out_size, void* d_ws, size_t ws_size,
                              hipStream_t stream)
{
    (void)n_in;
    const float* feat = (const float*)d_in[0];
    const float* w1   = (const float*)d_in[1];
    const float* w2   = (const float*)d_in[2];
    const float* w3   = (const float*)d_in[3];
    const float* locs = (const float*)d_in[4];
    const int*   eidx = (const int*)d_in[5];
    float* out  = (float*)d_out;

    const int E = in_sizes[4] / 2;
    if (E <= 0) return;

    __bf16* w3t   = (__bf16*)((char*)d_ws + WS_W3T_OFF);
    __bf16* w2t   = (__bf16*)((char*)d_ws + WS_W2T_OFF);
    __bf16* featT = (__bf16*)((char*)d_ws + WS_FEATT_OFF);

    int nblocks = (E + ROWS - 1) / ROWS;

    if (ws_size >= (size_t)WS_NEED) {
        qc_prep2_kernel<<<1296, 256, 0, stream>>>(w3, w2, feat, out, w3t, w2t, featT);
        qc_fused_kernel<<<nblocks, 512, 0, stream>>>(featT, w1, locs, eidx, w2t, w3t, out, E);
    } else {
        int n4 = out_size / 4;
        qc_zero_kernel<<<(n4 + 255) / 256, 256, 0, stream>>>(out, n4);
        qc_prep_kernel<<<272, 256, 0, stream>>>(w3, w2, w3t, w2t);
        qc_main_kernel<<<nblocks, 256, 0, stream>>>(feat, w1, w2, locs, eidx, w3t, out, E);
    }
}

// Round 8
// 150.942 us; speedup vs baseline: 3.5149x; 3.5149x over previous
//
#include <hip/hip_runtime.h>
#include <hip/hip_bf16.h>

typedef __bf16 bf16x8  __attribute__((ext_vector_type(8)));
typedef __bf16 bf16x16 __attribute__((ext_vector_type(16)));
typedef float  f32x4   __attribute__((ext_vector_type(4)));

#define N_IN   4096
#define N_OUT  1024
#define BATCH  16
#define ROWS   16

// LDS strides in __bf16 elements
#define H1_STR   72     // 64 + 8
#define H2_STR   72
#define FT_JSTR  40     // 32 + 8  (i-stride inside a j-row of half-ftv)
#define FTH_NSTR 640    // 16*40 (half: 16 j's per pass)
#define G_STR    520    // 512 + 8
#define V_STR    520

// ws layout:
//   [0,131072)       w3t  bf16 (1024x64)       w3t[col*64+k]
//   [131072,139264)  w2t  bf16 (64x64)         w2t[col*64+k]
//   [139264,4333568) featT bf16 (32*4096*16)   featT[((c*4096+src)*16)+b]
#define WS_W3T_OFF    0
#define WS_W2T_OFF    131072
#define WS_FEATT_OFF  139264
#define WS_NEED       4333568

__global__ void qc_zero_kernel(float* __restrict__ out, int n4) {
    int i = blockIdx.x * blockDim.x + threadIdx.x;
    if (i < n4) ((float4*)out)[i] = make_float4(0.f, 0.f, 0.f, 0.f);
}

// Fallback prep: w3t/w2t only
__global__ void qc_prep_kernel(const float* __restrict__ w3, const float* __restrict__ w2,
                               __bf16* __restrict__ w3t, __bf16* __restrict__ w2t) {
    int gid = blockIdx.x * blockDim.x + threadIdx.x;
    if (gid < 65536) {
        int k = gid & 63, col = gid >> 6;
        w3t[gid] = (__bf16)w3[k * 1024 + col];
    } else {
        int j = gid - 65536;
        int k = j & 63, col = j >> 6;
        w2t[j] = (__bf16)w2[k * 64 + col];
    }
}

// Fused prep: zero out (512 blks) + w3t (256) + w2t (16) + featT transpose (512)
__global__ void qc_prep2_kernel(const float* __restrict__ w3, const float* __restrict__ w2,
                                const float* __restrict__ feat,
                                float* __restrict__ out,
                                __bf16* __restrict__ w3t, __bf16* __restrict__ w2t,
                                __bf16* __restrict__ featT) {
    int bid = blockIdx.x, tid = threadIdx.x;
    if (bid < 512) {
        int i = bid * 256 + tid;                     // 131072 float4s
        ((float4*)out)[i] = make_float4(0.f, 0.f, 0.f, 0.f);
    } else if (bid < 768) {
        int gid = (bid - 512) * 256 + tid;           // 65536
        int k = gid & 63, col = gid >> 6;
        w3t[gid] = (__bf16)w3[k * 1024 + col];
    } else if (bid < 784) {
        int j = (bid - 768) * 256 + tid;             // 4096
        int k = j & 63, col = j >> 6;
        w2t[j] = (__bf16)w2[k * 64 + col];
    } else {
        // featT[c][src][b] = feat[b][c][src]; 512 blocks cover 32 c x 16 chunks
        int bid2 = bid - 784;                        // 0..511
        int c    = bid2 >> 4;                        // 0..31
        int src  = (bid2 & 15) * 256 + tid;          // 0..4095
        bf16x16 v;
        #pragma unroll
        for (int b = 0; b < 16; ++b)                 // coalesced dword loads per b
            v[b] = (__bf16)feat[(b * 32 + c) * N_IN + src];
        __bf16* p = &featT[((size_t)c * N_IN + src) * 16];   // 32B/thread, coalesced
        *(bf16x8*)p       = *(bf16x8*)&v;
        *(bf16x8*)(p + 8) = *((bf16x8*)&v + 1);
    }
}

// ---------------------------------------------------------------------------
// Fused kernel: 512 threads per 16-row tile, half-size ftv (two C/D passes)
// -> 42.75 KB LDS -> 3 blocks/CU.
//   gather issue + idx/h1 -> S1 -> h2 (MFMA) -> S2 -> park gather ->
//   C-pass0 (j<16) -> S3a -> D-load ag,f0 + MFMA c0 -> S3b ->
//   C-pass1 (j>=16, overwrite ftv) -> S3c -> D-load f1 + MFMA c1 ->
//   vals overlay gb -> S4 -> register run-merged atomic scatter (R5-proven).
// ---------------------------------------------------------------------------
__global__ __launch_bounds__(512, 6)
void qc_fused_kernel(const __bf16* __restrict__ featT,
                     const float* __restrict__ w1,
                     const float* __restrict__ locs,
                     const int*   __restrict__ eidx,
                     const __bf16* __restrict__ w2t,
                     const __bf16* __restrict__ w3t,
                     float* __restrict__ out,
                     int E)
{
    __shared__ __align__(16) __bf16 h1b[ROWS * H1_STR];    // 2304 B
    __shared__ __align__(16) __bf16 h2b[ROWS * H2_STR];    // 2304 B
    __shared__ __align__(16) __bf16 ftv[ROWS * FTH_NSTR];  // 20480 B
    __shared__ __align__(16) __bf16 gb [BATCH * G_STR];    // 16640 B (later: vals)
    __shared__ unsigned short seg_s[512];                  // 1024 B
    // total 42752 B -> 3 blocks/CU (24 waves, 75%)

    const int tid = threadIdx.x;
    const int n0  = blockIdx.x * ROWS;
    const int t0  = n0 * 32;
    const int ch0 = t0 / E;
    const int m0  = t0 - ch0 * E;          // block spans <512 t's -> at most one wrap

    // ---- Gather: ONE 32B load per thread (all 16 batches), issued first ----
    int mm = m0 + tid;
    const int cc = ch0 + (mm >= E);
    if (mm >= E) mm -= E;
    int2 p = ((const int2*)eidx)[mm];      // .x = seg, .y = src
    bf16x16 gv = {};
    if (cc < 32)
        gv = *(const bf16x16*)&featT[((size_t)cc * N_IN + p.y) * 16];
    seg_s[tid] = (unsigned short)p.x;

    // ---- Phase A: h1 = sin(loc @ W1) ----
    {
        const int r  = tid >> 5;
        const int j0 = (tid & 31) * 2;
        float lx = 0.f, ly = 0.f;
        int n = n0 + r;
        if (n < E) { lx = locs[n * 2]; ly = locs[n * 2 + 1]; }
        float2 wa = *(const float2*)&w1[j0];
        float2 wb = *(const float2*)&w1[64 + j0];
        __bf16* h = &h1b[r * H1_STR + j0];
        h[0] = (__bf16)__sinf(lx * wa.x + ly * wb.x);
        h[1] = (__bf16)__sinf(lx * wa.y + ly * wb.y);
    }
    __syncthreads();   // S1

    const int lane = tid & 63;
    const int wv   = tid >> 6;      // 0..7
    const int ml   = lane & 15;
    const int q    = lane >> 4;

    // ---- Phase B: h2 = sin(h1 @ W2) via MFMA (waves 0..3, 16 cols each) ----
    if (wv < 4) {
        bf16x8 a0 = *(const bf16x8*)&h1b[ml * H1_STR + q * 8];
        bf16x8 a1 = *(const bf16x8*)&h1b[ml * H1_STR + 32 + q * 8];
        const __bf16* wp = &w2t[(wv * 16 + ml) * 64 + q * 8];
        bf16x8 b0 = *(const bf16x8*)wp;
        bf16x8 b1 = *(const bf16x8*)(wp + 32);
        f32x4 c = {0.f, 0.f, 0.f, 0.f};
        c = __builtin_amdgcn_mfma_f32_16x16x32_bf16(a0, b0, c, 0, 0, 0);
        c = __builtin_amdgcn_mfma_f32_16x16x32_bf16(a1, b1, c, 0, 0, 0);
        #pragma unroll
        for (int g_ = 0; g_ < 4; ++g_)
            h2b[(q * 4 + g_) * H2_STR + wv * 16 + ml] = (__bf16)__sinf(c[g_]);
    }
    __syncthreads();   // S2

    // ---- Park gathered batches into gb (stride-1 writes) ----
    #pragma unroll
    for (int b = 0; b < 16; ++b)
        gb[b * G_STR + tid] = gv[b];

    // A-operand fragments of h2 (reused in both C passes)
    bf16x8 ha0 = *(const bf16x8*)&h2b[ml * H2_STR + q * 8];
    bf16x8 ha1 = *(const bf16x8*)&h2b[ml * H2_STR + 32 + q * 8];

    bf16x8 ag[2];
    f32x4  c0[2], c1[2];

    // ---- C-pass0: filt cols j<16 -> ftv[n][j][i] (j = ml) ----
    #pragma unroll
    for (int tt = 0; tt < 4; ++tt) {
        int i_  = wv * 4 + tt;                 // 0..31
        int col = i_ * 32 + ml;                // j = ml < 16
        const __bf16* wp = &w3t[col * 64 + q * 8];
        bf16x8 b0 = *(const bf16x8*)wp;
        bf16x8 b1 = *(const bf16x8*)(wp + 32);
        f32x4 c = {0.f, 0.f, 0.f, 0.f};
        c = __builtin_amdgcn_mfma_f32_16x16x32_bf16(ha0, b0, c, 0, 0, 0);
        c = __builtin_amdgcn_mfma_f32_16x16x32_bf16(ha1, b1, c, 0, 0, 0);
        __bf16* fp = &ftv[ml * FT_JSTR + i_];
        fp[(q * 4 + 0) * FTH_NSTR] = (__bf16)c[0];
        fp[(q * 4 + 1) * FTH_NSTR] = (__bf16)c[1];
        fp[(q * 4 + 2) * FTH_NSTR] = (__bf16)c[2];
        fp[(q * 4 + 3) * FTH_NSTR] = (__bf16)c[3];
    }
    __syncthreads();   // S3a

    // ---- D-pass0: load ag + f0, MFMA c0 (j = ml) ----
    {
        bf16x8 f0[2];
        #pragma unroll
        for (int rr = 0; rr < 2; ++rr) {
            int r = wv * 2 + rr;
            f0[rr] = *(const bf16x8*)&ftv[r * FTH_NSTR + ml * FT_JSTR + q * 8];
            ag[rr] = *(const bf16x8*)&gb[ml * G_STR + r * 32 + q * 8];
        }
        #pragma unroll
        for (int rr = 0; rr < 2; ++rr) {
            f32x4 z = {0.f, 0.f, 0.f, 0.f};
            c0[rr] = __builtin_amdgcn_mfma_f32_16x16x32_bf16(ag[rr], f0[rr], z, 0, 0, 0);
        }
    }
    __syncthreads();   // S3b: all ftv/gb reads done

    // ---- C-pass1: filt cols j>=16 -> ftv (overwrite; store at j-16) ----
    #pragma unroll
    for (int tt = 0; tt < 4; ++tt) {
        int i_  = wv * 4 + tt;
        int col = i_ * 32 + 16 + ml;           // j = 16 + ml
        const __bf16* wp = &w3t[col * 64 + q * 8];
        bf16x8 b0 = *(const bf16x8*)wp;
        bf16x8 b1 = *(const bf16x8*)(wp + 32);
        f32x4 c = {0.f, 0.f, 0.f, 0.f};
        c = __builtin_amdgcn_mfma_f32_16x16x32_bf16(ha0, b0, c, 0, 0, 0);
        c = __builtin_amdgcn_mfma_f32_16x16x32_bf16(ha1, b1, c, 0, 0, 0);
        __bf16* fp = &ftv[ml * FT_JSTR + i_];
        fp[(q * 4 + 0) * FTH_NSTR] = (__bf16)c[0];
        fp[(q * 4 + 1) * FTH_NSTR] = (__bf16)c[1];
        fp[(q * 4 + 2) * FTH_NSTR] = (__bf16)c[2];
        fp[(q * 4 + 3) * FTH_NSTR] = (__bf16)c[3];
    }
    __syncthreads();   // S3c

    // ---- D-pass1: load f1, MFMA c1 (j = 16+ml); vals overlay gb ----
    {
        bf16x8 f1[2];
        #pragma unroll
        for (int rr = 0; rr < 2; ++rr) {
            int r = wv * 2 + rr;
            f1[rr] = *(const bf16x8*)&ftv[r * FTH_NSTR + ml * FT_JSTR + q * 8];
        }
        #pragma unroll
        for (int rr = 0; rr < 2; ++rr) {
            f32x4 z = {0.f, 0.f, 0.f, 0.f};
            c1[rr] = __builtin_amdgcn_mfma_f32_16x16x32_bf16(ag[rr], f1[rr], z, 0, 0, 0);
        }
        // gb reads all completed before S3b -> safe to overlay vals now
        __bf16* valsb = gb;
        #pragma unroll
        for (int rr = 0; rr < 2; ++rr) {
            int r = wv * 2 + rr;
            __bf16* vp = &valsb[r * 32];
            #pragma unroll
            for (int g_ = 0; g_ < 4; ++g_) {
                int b = q * 4 + g_;
                vp[b * V_STR + ml]      = (__bf16)c0[rr][g_];
                vp[b * V_STR + 16 + ml] = (__bf16)c1[rr][g_];
            }
        }
    }
    __syncthreads();   // S4

    // ---- Phase E: run-merged atomic scatter (512 thr x 16 vals, R5-proven) ----
    {
        const __bf16* valsb = gb;
        const int b    = tid >> 5;            // 0..15
        const int rem  = tid & 31;
        const int tl0  = (rem >> 1) * 32 + (rem & 1) * 16;
        const __bf16* vp = &valsb[b * V_STR + tl0];
        bf16x8 v0 = *(const bf16x8*)(vp);
        bf16x8 v1 = *(const bf16x8*)(vp + 8);
        float vv[16];
        #pragma unroll
        for (int j = 0; j < 8; ++j) { vv[j] = (float)v0[j]; vv[8 + j] = (float)v1[j]; }
        int key_prev = -1;
        float acc = 0.f;
        #pragma unroll
        for (int j = 0; j < 16; ++j) {
            int mm2 = m0 + tl0 + j;
            int cc2 = ch0 + (mm2 >= E);
            if (mm2 >= E) mm2 -= E;
            if (cc2 < 32) {
                int o   = (int)seg_s[tl0 + j];
                int key = ((b * 32 + cc2) << 10) | o;
                if (key != key_prev) {
                    if (key_prev >= 0) atomicAdd(&out[key_prev], acc);
                    key_prev = key;
                    acc = vv[j];
                } else {
                    acc += vv[j];
                }
            }
        }
        if (key_prev >= 0) atomicAdd(&out[key_prev], acc);
    }
}

// ---------------------------------------------------------------------------
// Fallback: round-1 fused kernel (used only if ws too small)
// ---------------------------------------------------------------------------
#define FB_FT_NSTR 1288
__global__ __launch_bounds__(256, 2)
void qc_main_kernel(const float* __restrict__ feat,
                    const float* __restrict__ w1,
                    const float* __restrict__ w2,
                    const float* __restrict__ locs,
                    const int*   __restrict__ eidx,
                    const __bf16* __restrict__ w3t,
                    float* __restrict__ out,
                    int E)
{
    __shared__ __align__(16) __bf16 h1b[ROWS * H1_STR];
    __shared__ __align__(16) __bf16 h2b[ROWS * H2_STR];
    __shared__ __align__(16) __bf16 ftv[ROWS * FB_FT_NSTR];
    __shared__ __align__(16) __bf16 gb [BATCH * G_STR];
    __shared__ unsigned short seg_s[512];
    __shared__ unsigned short src_s[512];

    const int tid = threadIdx.x;
    const int n0  = blockIdx.x * ROWS;
    const int t0  = n0 * 32;
    const int ch0 = t0 / E;
    const int m0  = t0 - ch0 * E;

    {
        const int r  = tid >> 4;
        const int j0 = (tid & 15) * 4;
        float lx = 0.f, ly = 0.f;
        int n = n0 + r;
        if (n < E) { lx = locs[n * 2]; ly = locs[n * 2 + 1]; }
        float4 wa = *(const float4*)&w1[j0];
        float4 wb = *(const float4*)&w1[64 + j0];
        __bf16* h = &h1b[r * H1_STR + j0];
        h[0] = (__bf16)__sinf(lx * wa.x + ly * wb.x);
        h[1] = (__bf16)__sinf(lx * wa.y + ly * wb.y);
        h[2] = (__bf16)__sinf(lx * wa.z + ly * wb.z);
        h[3] = (__bf16)__sinf(lx * wa.w + ly * wb.w);
    }
    for (int tl = tid; tl < 512; tl += 256) {
        int mm = m0 + tl; if (mm >= E) mm -= E;
        seg_s[tl] = (unsigned short)eidx[mm * 2];
        src_s[tl] = (unsigned short)eidx[mm * 2 + 1];
    }
    __syncthreads();

    {
        const int r  = tid >> 4;
        const int j0 = (tid & 15) * 4;
        float a0 = 0.f, a1 = 0.f, a2 = 0.f, a3 = 0.f;
        const __bf16* h1r = &h1b[r * H1_STR];
        #pragma unroll 8
        for (int k = 0; k < 64; ++k) {
            float h = (float)h1r[k];
            float4 w = *(const float4*)&w2[k * 64 + j0];
            a0 += h * w.x; a1 += h * w.y; a2 += h * w.z; a3 += h * w.w;
        }
        __bf16* h = &h2b[r * H2_STR + j0];
        h[0] = (__bf16)__sinf(a0);
        h[1] = (__bf16)__sinf(a1);
        h[2] = (__bf16)__sinf(a2);
        h[3] = (__bf16)__sinf(a3);
    }
    #pragma unroll 4
    for (int it = 0; it < 32; ++it) {
        int idx = it * 256 + tid;
        int b   = idx >> 9;
        int tl  = idx & 511;
        int mm  = m0 + tl;
        int cc  = ch0 + (mm >= E);
        if (mm >= E) mm -= E;
        float v = 0.f;
        if (cc < 32) v = feat[(b * 32 + cc) * N_IN + (int)src_s[tl]];
        gb[b * G_STR + tl] = (__bf16)v;
    }
    __syncthreads();

    const int lane = tid & 63;
    const int wv   = tid >> 6;
    const int ml   = lane & 15;
    const int q    = lane >> 4;

    {
        bf16x8 a0 = *(const bf16x8*)&h2b[ml * H2_STR + q * 8];
        bf16x8 a1 = *(const bf16x8*)&h2b[ml * H2_STR + 32 + q * 8];
        #pragma unroll
        for (int t = 0; t < 16; ++t) {
            int col = wv * 256 + t * 16 + ml;
            const __bf16* wp = &w3t[col * 64 + q * 8];
            bf16x8 b0 = *(const bf16x8*)wp;
            bf16x8 b1 = *(const bf16x8*)(wp + 32);
            f32x4 c = {0.f, 0.f, 0.f, 0.f};
            c = __builtin_amdgcn_mfma_f32_16x16x32_bf16(a0, b0, c, 0, 0, 0);
            c = __builtin_amdgcn_mfma_f32_16x16x32_bf16(a1, b1, c, 0, 0, 0);
            int i_ = col >> 5, j_ = col & 31;
            __bf16* fp = &ftv[j_ * FT_JSTR + i_];
            fp[(q * 4 + 0) * FB_FT_NSTR] = (__bf16)c[0];
            fp[(q * 4 + 1) * FB_FT_NSTR] = (__bf16)c[1];
            fp[(q * 4 + 2) * FB_FT_NSTR] = (__bf16)c[2];
            fp[(q * 4 + 3) * FB_FT_NSTR] = (__bf16)c[3];
        }
    }
    __syncthreads();

    {
        bf16x8 ag[4], f0[4], f1[4];
        #pragma unroll
        for (int rr = 0; rr < 4; ++rr) {
            int r = wv * 4 + rr;
            ag[rr] = *(const bf16x8*)&gb[ml * G_STR + r * 32 + q * 8];
            f0[rr] = *(const bf16x8*)&ftv[r * FB_FT_NSTR + ml        * FT_JSTR + q * 8];
            f1[rr] = *(const bf16x8*)&ftv[r * FB_FT_NSTR + (16 + ml) * FT_JSTR + q * 8];
        }
        __syncthreads();
        __bf16* valsb = ftv;
        #pragma unroll
        for (int rr = 0; rr < 4; ++rr) {
            int r = wv * 4 + rr;
            f32x4 c0 = {0.f, 0.f, 0.f, 0.f};
            f32x4 c1 = {0.f, 0.f, 0.f, 0.f};
            c0 = __builtin_amdgcn_mfma_f32_16x16x32_bf16(ag[rr], f0[rr], c0, 0, 0, 0);
            c1 = __builtin_amdgcn_mfma_f32_16x16x32_bf16(ag[rr], f1[rr], c1, 0, 0, 0);
            __bf16* vp = &valsb[r * 32];
            #pragma unroll
            for (int g_ = 0; g_ < 4; ++g_) {
                int b = q * 4 + g_;
                vp[b * V_STR + ml]      = (__bf16)c0[g_];
                vp[b * V_STR + 16 + ml] = (__bf16)c1[g_];
            }
        }
    }
    __syncthreads();

    {
        const __bf16* valsb = ftv;
        const int b = tid >> 4;
        const int r = tid & 15;
        const __bf16* vp = &valsb[b * V_STR + r * 32];
        bf16x8 v0 = *(const bf16x8*)(vp);
        bf16x8 v1 = *(const bf16x8*)(vp + 8);
        bf16x8 v2 = *(const bf16x8*)(vp + 16);
        bf16x8 v3 = *(const bf16x8*)(vp + 24);
        float vv[32];
        #pragma unroll
        for (int j = 0; j < 8; ++j) {
            vv[j]      = (float)v0[j];
            vv[8 + j]  = (float)v1[j];
            vv[16 + j] = (float)v2[j];
            vv[24 + j] = (float)v3[j];
        }
        const int tl0 = r * 32;
        int key_prev = -1;
        float acc = 0.f;
        #pragma unroll
        for (int j = 0; j < 32; ++j) {
            int mm = m0 + tl0 + j;
            int cc = ch0 + (mm >= E);
            if (mm >= E) mm -= E;
            if (cc < 32) {
                int o   = (int)seg_s[tl0 + j];
                int key = ((b * 32 + cc) << 10) | o;
                if (key != key_prev) {
                    if (key_prev >= 0) atomicAdd(&out[key_prev], acc);
                    key_prev = key;
                    acc = vv[j];
                } else {
                    acc += vv[j];
                }
            }
        }
        if (key_prev >= 0) atomicAdd(&out[key_prev], acc);
    }
}

extern "C" void kernel_launch(void* const* d_in, const int* in_sizes, int n_in,
                              void* d_out, int out_size, void* d_ws, size_t ws_size,
                              hipStream_t stream)
{
    (void)n_in;
    const float* feat = (const float*)d_in[0];
    const float* w1   = (const float*)d_in[1];
    const float* w2   = (const float*)d_in[2];
    const float* w3   = (const float*)d_in[3];
    const float* locs = (const float*)d_in[4];
    const int*   eidx = (const int*)d_in[5];
    float* out  = (float*)d_out;

    const int E = in_sizes[4] / 2;
    if (E <= 0) return;

    __bf16* w3t   = (__bf16*)((char*)d_ws + WS_W3T_OFF);
    __bf16* w2t   = (__bf16*)((char*)d_ws + WS_W2T_OFF);
    __bf16* featT = (__bf16*)((char*)d_ws + WS_FEATT_OFF);

    int nblocks = (E + ROWS - 1) / ROWS;

    if (ws_size >= (size_t)WS_NEED) {
        qc_prep2_kernel<<<1296, 256, 0, stream>>>(w3, w2, feat, out, w3t, w2t, featT);
        qc_fused_kernel<<<nblocks, 512, 0, stream>>>(featT, w1, locs, eidx, w2t, w3t, out, E);
    } else {
        int n4 = out_size / 4;
        qc_zero_kernel<<<(n4 + 255) / 256, 256, 0, stream>>>(out, n4);
        qc_prep_kernel<<<272, 256, 0, stream>>>(w3, w2, w3t, w2t);
        qc_main_kernel<<<nblocks, 256, 0, stream>>>(feat, w1, w2, locs, eidx, w3t, out, E);
    }
}